// Round 12
// baseline (258.860 us; speedup 1.0000x reference)
//
#include <hip/hip_runtime.h>
#include <hip/hip_bf16.h>
#include <hip/hip_cooperative_groups.h>

namespace cg = cooperative_groups;

#define ALPHA 0.2f
#define LOG2E 1.44269504f

// ws layout (bytes)
#define VB_OFFB 0                        // Vb: bf16 swizzled V, 6291456 B
#define XB_OFFB 6291456                  // Xb: bf16 X, 6291456 B
#define WB_OFFB (XB_OFFB + 6291456)      // Wb: bf16 swizzled W, 1179648 B
#define F1_OFFB (WB_OFFB + 1179648)      // f1: 32768 f32
#define F2_OFFB (F1_OFFB + 131072)       // f2: 32768 f32 (contiguous after f1)

typedef __attribute__((ext_vector_type(8))) unsigned short us8;
typedef __attribute__((ext_vector_type(8))) short s8;
typedef __attribute__((ext_vector_type(4))) float f32x4;

__device__ inline unsigned short f2bf(float x) {
    __hip_bfloat16 h = __float2bfloat16(x);
    return reinterpret_cast<unsigned short&>(h);
}

__device__ __forceinline__ void gload16(const void* g, void* lds) {
    __builtin_amdgcn_global_load_lds((const unsigned int*)g, (unsigned int*)lds,
                                     16, 0, 0);
}

// ---------------------------------------------------------------------------
// prep_unit: virtual block u of preprocessing.
//   u 0..1535:    X fp32 -> Xb bf16 (row-major)
//   u 1536..1823: W fp32 -> Wb bf16 B-frag order
//   u 1824..2079: zero f1/f2 (65536 contiguous floats)
// ---------------------------------------------------------------------------
__device__ __forceinline__ void prep_unit(int u, const float* __restrict__ X,
                                          const float* __restrict__ W,
                                          unsigned short* __restrict__ Xb,
                                          unsigned short* __restrict__ Wb,
                                          float* __restrict__ f12z) {
    if (u < 1536) {
        const int i = (u * 256 + threadIdx.x) * 8;
        float4 v0 = *(const float4*)&X[i];
        float4 v1 = *(const float4*)&X[i + 4];
        ushort4 p0, p1;
        p0.x = f2bf(v0.x); p0.y = f2bf(v0.y); p0.z = f2bf(v0.z); p0.w = f2bf(v0.w);
        p1.x = f2bf(v1.x); p1.y = f2bf(v1.y); p1.z = f2bf(v1.z); p1.w = f2bf(v1.w);
        *(ushort4*)&Xb[i] = p0;
        *(ushort4*)&Xb[i + 4] = p1;
    } else if (u < 1824) {
        const int id = (u - 1536) * 256 + threadIdx.x;   // 0..73727
        const int l = id & 63;
        const int ks = (id >> 6) & 1;
        const int cg4 = (id >> 7) & 3;
        const int kc = id >> 9;                          // kt*12 + ct
        const int kt = kc / 12;
        const int ct = kc - kt * 12;
        const int k0 = kt * 64 + ks * 32 + (l >> 4) * 8;
        const int n = ct * 64 + cg4 * 16 + (l & 15);
        ushort4 p0, p1;
        p0.x = f2bf(W[(size_t)(k0 + 0) * 768 + n]);
        p0.y = f2bf(W[(size_t)(k0 + 1) * 768 + n]);
        p0.z = f2bf(W[(size_t)(k0 + 2) * 768 + n]);
        p0.w = f2bf(W[(size_t)(k0 + 3) * 768 + n]);
        p1.x = f2bf(W[(size_t)(k0 + 4) * 768 + n]);
        p1.y = f2bf(W[(size_t)(k0 + 5) * 768 + n]);
        p1.z = f2bf(W[(size_t)(k0 + 6) * 768 + n]);
        p1.w = f2bf(W[(size_t)(k0 + 7) * 768 + n]);
        *(ushort4*)&Wb[(size_t)id * 8 + 0] = p0;
        *(ushort4*)&Wb[(size_t)id * 8 + 4] = p1;
    } else {
        const int idx = (u - 1824) * 256 + threadIdx.x;  // 0..65535
        f12z[idx] = 0.f;
    }
}

// ---------------------------------------------------------------------------
// gemm_body: round-4 verified LDS gemm tile (coalesced global_load_lds,
// A-side XOR swizzle, lane-linear Wb) + Vb swizzled store + f1/f2 atomic
// epilogue. smem: 32 KB (Xs 2x8KB at +0, Ws 2x8KB at +16384).
// ---------------------------------------------------------------------------
__device__ __forceinline__ void gemm_body(int bid,
                                          const unsigned short* __restrict__ Xb,
                                          const unsigned short* __restrict__ Wb,
                                          const float* __restrict__ a,
                                          unsigned short* __restrict__ Vb,
                                          float* __restrict__ f1,
                                          float* __restrict__ f2,
                                          unsigned char* smem) {
    unsigned char* XsB = smem;           // [2][8192] bytes
    unsigned char* WsB = smem + 16384;   // [2][8192] bytes

    const int tid = threadIdx.x;
    const int l = tid & 63;
    const int w = tid >> 6;
    const int wr = w >> 1, wc = w & 1;
    const int nid = (bid & 7) * 96 + (bid >> 3);   // XCD-chunked bijective
    const int bx = nid % 12;             // N-tile (64 cols)
    const int row0 = (nid / 12) * 64;    // M-tile (64 rows)

    const int xrow_base = w * 16 + (l >> 3);
    const int xkb_log8 = ((l & 7) ^ (l >> 3)) * 8;

    f32x4 acc[2][2];
#pragma unroll
    for (int i = 0; i < 2; ++i)
#pragma unroll
        for (int j = 0; j < 2; ++j) acc[i][j] = (f32x4){0.f, 0.f, 0.f, 0.f};

#pragma unroll
    for (int q = 0; q < 2; ++q) {
        const int g16 = w * 2 + q;
        gload16(Xb + (size_t)(row0 + xrow_base + q * 8) * 768 + xkb_log8,
                XsB + g16 * 1024);
        gload16(Wb + (size_t)(0 * 12 + bx) * 4096 + g16 * 512 + l * 8,
                WsB + g16 * 1024);
    }

    int buf = 0;
    for (int kt = 0; kt < 12; ++kt) {
        __syncthreads();
        if (kt < 11) {
            const int k0n = (kt + 1) * 64;
#pragma unroll
            for (int q = 0; q < 2; ++q) {
                const int g16 = w * 2 + q;
                gload16(Xb + (size_t)(row0 + xrow_base + q * 8) * 768 + k0n + xkb_log8,
                        XsB + (buf ^ 1) * 8192 + g16 * 1024);
                gload16(Wb + (size_t)((kt + 1) * 12 + bx) * 4096 + g16 * 512 + l * 8,
                        WsB + (buf ^ 1) * 8192 + g16 * 1024);
            }
        }
#pragma unroll
        for (int ks = 0; ks < 2; ++ks) {
            s8 af[2], bfr[2];
#pragma unroll
            for (int fr = 0; fr < 2; ++fr) {
                const int row = wr * 32 + fr * 16 + (l & 15);
                const int slot = (ks * 4 + (l >> 4)) ^ (row & 7);
                af[fr] = *(const s8*)(XsB + buf * 8192 + row * 128 + slot * 16);
            }
#pragma unroll
            for (int cg2 = 0; cg2 < 2; ++cg2) {
                bfr[cg2] = *(const s8*)(WsB + buf * 8192 +
                                        (((wc * 2 + cg2) * 2 + ks) * 64 + l) * 16);
            }
#pragma unroll
            for (int fr = 0; fr < 2; ++fr)
#pragma unroll
                for (int cg2 = 0; cg2 < 2; ++cg2)
                    acc[fr][cg2] = __builtin_amdgcn_mfma_f32_16x16x32_bf16(
                        af[fr], bfr[cg2], acc[fr][cg2], 0, 0, 0);
        }
        buf ^= 1;
    }

    // Epilogue 1: Vb swizzled bf16 store. C/D: col=l&15, row=(l>>4)*4+reg.
#pragma unroll
    for (int fr = 0; fr < 2; ++fr) {
#pragma unroll
        for (int cg2 = 0; cg2 < 2; ++cg2) {
            const int jglob = row0 + wr * 32 + fr * 16 + (l >> 4) * 4;
            const int b = jglob >> 10;
            const int jn = jglob & 1023;
            const int jc = jn >> 7;
            const int ks4 = (jn >> 5) & 3;
            const int kg = (jn >> 3) & 3;
            const int e0 = jn & 7;
            const int g0 = bx * 64 + wc * 32 + cg2 * 16;
            const int h = g0 / 96;
            const int ft = (g0 - h * 96) >> 4;
            const int fc = l & 15;
            const size_t ibase =
                (((((size_t)(b * 8 + h) * 8 + jc) * 4 + ks4) * 4 + kg) * 6 + ft) * 128 +
                fc * 8 + e0;
            ushort4 pk;
            pk.x = f2bf(acc[fr][cg2][0]);
            pk.y = f2bf(acc[fr][cg2][1]);
            pk.z = f2bf(acc[fr][cg2][2]);
            pk.w = f2bf(acc[fr][cg2][3]);
            *(ushort4*)&Vb[ibase] = pk;
        }
    }

    // Epilogue 2: f1/f2 partial sums (verified round 10/11).
#pragma unroll
    for (int cg2 = 0; cg2 < 2; ++cg2) {
        const int c = bx * 64 + wc * 32 + cg2 * 16 + (l & 15);
        const int h = c / 96;
        const int f = c - h * 96;
        const float av1 = a[f];
        const float av2 = a[96 + f];
#pragma unroll
        for (int fr = 0; fr < 2; ++fr) {
            const int jglob = row0 + wr * 32 + fr * 16 + (l >> 4) * 4;
            const int b = jglob >> 10;
            const int n0 = jglob & 1023;
#pragma unroll
            for (int r = 0; r < 4; ++r) {
                float s1 = acc[fr][cg2][r] * av1;
                float s2 = acc[fr][cg2][r] * av2;
#pragma unroll
                for (int m = 1; m < 16; m <<= 1) {
                    s1 += __shfl_xor(s1, m);
                    s2 += __shfl_xor(s2, m);
                }
                if ((l & 15) == 0) {
                    const int idx = (((b << 3) + h) << 10) | (n0 + r);
                    atomicAdd(&f1[idx], s1);
                    atomicAdd(&f2[idx], s2);
                }
            }
        }
    }
}

// ---------------------------------------------------------------------------
// attn_body: round-8 verified V-reuse attention tile. smem: Vs 2x24576 B at
// +0, g2 (1024 f32) passed separately (at +49152 in callers).
// ---------------------------------------------------------------------------
__device__ __forceinline__ void attn_body(int bid,
                                          const unsigned short* __restrict__ Vb,
                                          const float* __restrict__ f1,
                                          const float* __restrict__ f2,
                                          const int* __restrict__ mask,
                                          float* __restrict__ out,
                                          unsigned char* VsB, float* g2_s) {
    const int tid = threadIdx.x;
    const int lane = tid & 63;
    const int w = tid >> 6;
    const int kg = lane >> 4;
    const int fcr = lane & 15;
    const int nid = (bid & 7) * 64 + (bid >> 3);   // XCD-bijective
    const int it = nid & 15;       // 16 i-tiles of 64 rows
    const int bh = nid >> 4;
    const int b = bh >> 3;
    const int h = bh & 7;

    const size_t vbase = (size_t)bh * 98304;

    for (int j = tid; j < 1024; j += 256) {
        float fv = f2[bh * 1024 + j] * LOG2E;
        g2_s[j] = (mask[b * 1024 + j] != 0) ? fv : -20000.f;
    }

    const float f1v = f1[bh * 1024 + it * 64 + w * 16 + fcr] * LOG2E;

#pragma unroll
    for (int r = 0; r < 6; ++r) {
        const int s = r * 256 + tid;           // 16B slot 0..1535
        gload16(Vb + vbase + (size_t)s * 8, VsB + s * 16);
    }

    f32x4 acc[6];
#pragma unroll
    for (int ft = 0; ft < 6; ++ft) acc[ft] = (f32x4){0.f, 0.f, 0.f, 0.f};
    float ls = 0.f;

    int buf = 0;
    for (int c = 0; c < 8; ++c) {
        __syncthreads();
        if (c < 7) {
#pragma unroll
            for (int r = 0; r < 6; ++r) {
                const int s = r * 256 + tid;
                gload16(Vb + vbase + (size_t)(c + 1) * 12288 + (size_t)s * 8,
                        VsB + (buf ^ 1) * 24576 + s * 16);
            }
        }
        const unsigned char* vsb = VsB + buf * 24576;
#pragma unroll
        for (int ks = 0; ks < 4; ++ks) {
            s8 af;
            const int jb = c * 128 + ks * 32 + kg * 8;
            float4 ga = *(const float4*)&g2_s[jb];
            float4 gb = *(const float4*)&g2_s[jb + 4];
            float g[8] = {ga.x, ga.y, ga.z, ga.w, gb.x, gb.y, gb.z, gb.w};
#pragma unroll
            for (int e = 0; e < 8; ++e) {
                float t = f1v + g[e];
                float lr = fmaxf(t, 0.f) + ALPHA * fminf(t, 0.f);
                float pe = exp2f(lr);
                ls += pe;
                af[e] = (short)f2bf(pe);
            }
            const unsigned char* vp = vsb + ((ks * 4 + kg) * 6) * 256 + fcr * 16;
#pragma unroll
            for (int ft = 0; ft < 6; ++ft) {
                us8 bvu = *(const us8*)(vp + ft * 256);
                acc[ft] = __builtin_amdgcn_mfma_f32_16x16x32_bf16(
                    af, (s8)bvu, acc[ft], 0, 0, 0);
            }
        }
        buf ^= 1;
    }

    ls += __shfl_xor(ls, 16);
    ls += __shfl_xor(ls, 32);
    float inv[4];
#pragma unroll
    for (int r = 0; r < 4; ++r) inv[r] = 1.0f / __shfl(ls, kg * 4 + r);

    const int irow0 = it * 64 + w * 16 + kg * 4;
#pragma unroll
    for (int r = 0; r < 4; ++r) {
        const size_t ob = (size_t)(b * 1024 + irow0 + r) * 768 + h * 96 + fcr;
#pragma unroll
        for (int ft = 0; ft < 6; ++ft) {
            out[ob + ft * 16] = acc[ft][r] * inv[r];
        }
    }
}

// ---------------------------------------------------------------------------
// Fused cooperative kernel: prep -> gridsync -> gemm -> gridsync -> attn.
// Grid 512 x 256, 52 KB LDS, launch_bounds(256,2) for co-residency.
// ---------------------------------------------------------------------------
__global__ __launch_bounds__(256, 2) void fused_all(
        const float* __restrict__ X, const float* __restrict__ W,
        const float* __restrict__ a, const int* __restrict__ mask,
        float* __restrict__ out, unsigned short* __restrict__ Xb,
        unsigned short* __restrict__ Wb, unsigned short* __restrict__ Vb,
        float* __restrict__ f1, float* __restrict__ f2) {
    __shared__ __align__(16) unsigned char smem[53248];

    for (int u = blockIdx.x; u < 2080; u += 512)
        prep_unit(u, X, W, Xb, Wb, f1);

    __threadfence();
    cg::this_grid().sync();

    for (int t = blockIdx.x; t < 768; t += 512)
        gemm_body(t, Xb, Wb, a, Vb, f1, f2, smem);

    __threadfence();
    cg::this_grid().sync();
    __threadfence();

    attn_body(blockIdx.x, Vb, f1, f2, mask, out, smem, (float*)(smem + 49152));
}

// ---------------------------------------------------------------------------
// Fallback standalone kernels (identical math) if cooperative launch fails.
// ---------------------------------------------------------------------------
__global__ __launch_bounds__(256) void prep_all_k(const float* __restrict__ X,
                                                  const float* __restrict__ W,
                                                  unsigned short* __restrict__ Xb,
                                                  unsigned short* __restrict__ Wb,
                                                  float* __restrict__ f12z) {
    prep_unit(blockIdx.x, X, W, Xb, Wb, f12z);
}

__global__ __launch_bounds__(256) void gemm_k(const unsigned short* __restrict__ Xb,
                                              const unsigned short* __restrict__ Wb,
                                              const float* __restrict__ a,
                                              unsigned short* __restrict__ Vb,
                                              float* __restrict__ f1,
                                              float* __restrict__ f2) {
    __shared__ __align__(16) unsigned char smem[32768];
    gemm_body(blockIdx.x, Xb, Wb, a, Vb, f1, f2, smem);
}

__global__ __launch_bounds__(256) void attn_k(const unsigned short* __restrict__ Vb,
                                              const float* __restrict__ f1,
                                              const float* __restrict__ f2,
                                              const int* __restrict__ mask,
                                              float* __restrict__ out) {
    __shared__ __align__(16) unsigned char smem[53248];
    attn_body(blockIdx.x, Vb, f1, f2, mask, out, smem, (float*)(smem + 49152));
}

extern "C" void kernel_launch(void* const* d_in, const int* in_sizes, int n_in,
                              void* d_out, int out_size, void* d_ws, size_t ws_size,
                              hipStream_t stream) {
    const float* X = (const float*)d_in[0];
    const int* mask = (const int*)d_in[1];
    const float* W = (const float*)d_in[2];
    const float* a = (const float*)d_in[3];
    float* out = (float*)d_out;
    char* ws = (char*)d_ws;

    unsigned short* Vb = (unsigned short*)(ws + VB_OFFB);
    unsigned short* Xb = (unsigned short*)(ws + XB_OFFB);
    unsigned short* Wb = (unsigned short*)(ws + WB_OFFB);
    float* f1 = (float*)(ws + F1_OFFB);
    float* f2 = (float*)(ws + F2_OFFB);

    void* args[10];
    args[0] = (void*)&X;   args[1] = (void*)&W;   args[2] = (void*)&a;
    args[3] = (void*)&mask; args[4] = (void*)&out; args[5] = (void*)&Xb;
    args[6] = (void*)&Wb;  args[7] = (void*)&Vb;  args[8] = (void*)&f1;
    args[9] = (void*)&f2;

    hipError_t err = hipLaunchCooperativeKernel((void*)fused_all, dim3(512),
                                                dim3(256), args, 0, stream);
    if (err != hipSuccess) {
        (void)hipGetLastError();   // clear sticky error; use 3-kernel path
        prep_all_k<<<2080, 256, 0, stream>>>(X, W, Xb, Wb, f1);
        gemm_k<<<768, 256, 0, stream>>>(Xb, Wb, a, Vb, f1, f2);
        attn_k<<<512, 256, 0, stream>>>(Vb, f1, f2, mask, out);
    }
}

// Round 13
// 56.998 us; speedup vs baseline: 4.5415x; 4.5415x over previous
//
#include <hip/hip_runtime.h>
#include <hip/hip_bf16.h>

#define ALPHA 0.2f
#define LOG2E 1.44269504f

// ws layout (bytes)
#define VB_OFFB 0                        // Vb: bf16 swizzled V, 6291456 B
#define F1P_OFFB 6291456                 // f1p: [4096][48] f32, 786432 B
#define F2P_OFFB (F1P_OFFB + 786432)     // f2p: [4096][48] f32, 786432 B

typedef __attribute__((ext_vector_type(8))) unsigned short us8;
typedef __attribute__((ext_vector_type(8))) short s8;
typedef __attribute__((ext_vector_type(4))) float f32x4;

__device__ inline unsigned short f2bf(float x) {
    __hip_bfloat16 h = __float2bfloat16(x);
    return reinterpret_cast<unsigned short&>(h);
}
__device__ inline short f2bfs(float x) { return (short)f2bf(x); }

__device__ __forceinline__ void gload16(const void* g, void* lds) {
    __builtin_amdgcn_global_load_lds((const unsigned int*)g, (unsigned int*)lds,
                                     16, 0, 0);
}

// ---------------------------------------------------------------------------
// gemm_np: no-prep fused GEMM. Stages fp32 X (XOR-swizzled segs) and fp32 W
// (linear) via global_load_lds into 64KB dbuf LDS; converts to bf16 at
// frag-read. Outputs: Vb (swizzled bf16, round-4 verified layout) and
// f1p/f2p partial slices (fp32, no atomics, unique writer per (row,g)).
// Grid 768 (XCD-chunked bijective swizzle), 4 waves of 32x32.
// ---------------------------------------------------------------------------
__global__ __launch_bounds__(256) void gemm_np(const float* __restrict__ X,
                                               const float* __restrict__ W,
                                               const float* __restrict__ a,
                                               unsigned short* __restrict__ Vb,
                                               float* __restrict__ f1p,
                                               float* __restrict__ f2p) {
    __shared__ __align__(16) unsigned char smem[65536];
    unsigned char* XsB = smem;           // fp32 [2][64 rows][64 k] (swizzled segs)
    unsigned char* WsB = smem + 32768;   // fp32 [2][64 k][64 n] (linear)

    const int tid = threadIdx.x;
    const int l = tid & 63;
    const int w = tid >> 6;
    const int wr = w >> 1, wc = w & 1;
    const int nid = (blockIdx.x & 7) * 96 + (blockIdx.x >> 3);
    const int bx = nid % 12;             // N-tile (64 cols)
    const int row0 = (nid / 12) * 64;    // M-tile (64 rows)

    const int srow = l >> 4;             // row within 4-row call group
    const int ssl = l & 15;              // phys 16B seg

    f32x4 acc[2][2];
#pragma unroll
    for (int i = 0; i < 2; ++i)
#pragma unroll
        for (int j = 0; j < 2; ++j) acc[i][j] = (f32x4){0.f, 0.f, 0.f, 0.f};

    // prologue: stage kt=0 into buf 0 (16 calls X + 16 calls W, 4 per wave)
#pragma unroll
    for (int q = 0; q < 4; ++q) {
        const int c = w * 4 + q;
        const int row = c * 4 + srow;                 // 0..63
        const int sl = ssl ^ (row & 7);               // pre-swizzled source seg
        gload16(X + (size_t)(row0 + row) * 768 + sl * 4, XsB + c * 1024);
        gload16(W + (size_t)row * 768 + bx * 64 + ssl * 4, WsB + c * 1024);
    }

    int buf = 0;
    for (int kt = 0; kt < 12; ++kt) {
        __syncthreads();   // drains vmcnt -> buf ready; prev compute done
        if (kt < 11) {
            const int kb = (kt + 1) * 64;
#pragma unroll
            for (int q = 0; q < 4; ++q) {
                const int c = w * 4 + q;
                const int row = c * 4 + srow;
                const int sl = ssl ^ (row & 7);
                gload16(X + (size_t)(row0 + row) * 768 + kb + sl * 4,
                        XsB + (buf ^ 1) * 16384 + c * 1024);
                gload16(W + (size_t)(kb + row) * 768 + bx * 64 + ssl * 4,
                        WsB + (buf ^ 1) * 16384 + c * 1024);
            }
        }
        const unsigned char* Xt = XsB + buf * 16384;
        const unsigned char* Wt = WsB + buf * 16384;
#pragma unroll
        for (int ks = 0; ks < 2; ++ks) {
            s8 af[2], bfr[2];
#pragma unroll
            for (int fr = 0; fr < 2; ++fr) {
                const int r = wr * 32 + fr * 16 + (l & 15);
                const int s0 = ks * 8 + (l >> 4) * 2;     // logical 16B seg
                f32x4 va = *(const f32x4*)(Xt + r * 256 + ((s0 ^ (r & 7)) << 4));
                f32x4 vb = *(const f32x4*)(Xt + r * 256 + (((s0 + 1) ^ (r & 7)) << 4));
                af[fr][0] = f2bfs(va[0]); af[fr][1] = f2bfs(va[1]);
                af[fr][2] = f2bfs(va[2]); af[fr][3] = f2bfs(va[3]);
                af[fr][4] = f2bfs(vb[0]); af[fr][5] = f2bfs(vb[1]);
                af[fr][6] = f2bfs(vb[2]); af[fr][7] = f2bfs(vb[3]);
            }
#pragma unroll
            for (int cg = 0; cg < 2; ++cg) {
                const int n = wc * 32 + cg * 16 + (l & 15);
                const int k0 = ks * 32 + (l >> 4) * 8;
                s8 bv;
#pragma unroll
                for (int e = 0; e < 8; ++e)
                    bv[e] = f2bfs(*(const float*)(Wt + (k0 + e) * 256 + n * 4));
                bfr[cg] = bv;
            }
#pragma unroll
            for (int fr = 0; fr < 2; ++fr)
#pragma unroll
                for (int cg = 0; cg < 2; ++cg)
                    acc[fr][cg] = __builtin_amdgcn_mfma_f32_16x16x32_bf16(
                        af[fr], bfr[cg], acc[fr][cg], 0, 0, 0);
        }
        buf ^= 1;
    }

    // Epilogue 1: Vb swizzled bf16 store. C/D: col=l&15, row=(l>>4)*4+reg.
#pragma unroll
    for (int fr = 0; fr < 2; ++fr) {
#pragma unroll
        for (int cg = 0; cg < 2; ++cg) {
            const int jglob = row0 + wr * 32 + fr * 16 + (l >> 4) * 4;
            const int b = jglob >> 10;
            const int jn = jglob & 1023;
            const int jc = jn >> 7;
            const int ks4 = (jn >> 5) & 3;
            const int kg = (jn >> 3) & 3;
            const int e0 = jn & 7;
            const int g0 = bx * 64 + wc * 32 + cg * 16;
            const int h = g0 / 96;
            const int ft = (g0 - h * 96) >> 4;
            const int fc = l & 15;
            const size_t ibase =
                (((((size_t)(b * 8 + h) * 8 + jc) * 4 + ks4) * 4 + kg) * 6 + ft) * 128 +
                fc * 8 + e0;
            ushort4 pk;
            pk.x = f2bf(acc[fr][cg][0]);
            pk.y = f2bf(acc[fr][cg][1]);
            pk.z = f2bf(acc[fr][cg][2]);
            pk.w = f2bf(acc[fr][cg][3]);
            *(ushort4*)&Vb[ibase] = pk;
        }
    }

    // Epilogue 2: f1/f2 partial slices (fp32, no atomics). Group g covers
    // cols g*16..+15 (16 | 96 -> single head per group).
#pragma unroll
    for (int cg = 0; cg < 2; ++cg) {
        const int c = bx * 64 + wc * 32 + cg * 16 + (l & 15);
        const int h = c / 96;
        const int f = c - h * 96;
        const float av1 = a[f];
        const float av2 = a[96 + f];
        const int g = bx * 4 + wc * 2 + cg;
#pragma unroll
        for (int fr = 0; fr < 2; ++fr) {
            const int jglob = row0 + wr * 32 + fr * 16 + (l >> 4) * 4;
#pragma unroll
            for (int r = 0; r < 4; ++r) {
                float s1 = acc[fr][cg][r] * av1;
                float s2 = acc[fr][cg][r] * av2;
#pragma unroll
                for (int m = 1; m < 16; m <<= 1) {
                    s1 += __shfl_xor(s1, m);
                    s2 += __shfl_xor(s2, m);
                }
                if ((l & 15) == 0) {
                    f1p[(size_t)(jglob + r) * 48 + g] = s1;
                    f2p[(size_t)(jglob + r) * 48 + g] = s2;
                }
            }
        }
    }
}

// ---------------------------------------------------------------------------
// attn8_k: round-8 verified V-reuse attention; prologue sums the 6 fp32
// partial slices per row instead of reading pre-reduced f1/f2.
// ---------------------------------------------------------------------------
__global__ __launch_bounds__(256) void attn8_k(const unsigned short* __restrict__ Vb,
                                               const float* __restrict__ f1p,
                                               const float* __restrict__ f2p,
                                               const int* __restrict__ mask,
                                               float* __restrict__ out) {
    __shared__ __align__(16) unsigned short Vs[2][12288];
    __shared__ float g2_s[1024];

    const int tid = threadIdx.x;
    const int lane = tid & 63;
    const int w = tid >> 6;
    const int kg = lane >> 4;
    const int fcr = lane & 15;
    const int nid = (blockIdx.x & 7) * 64 + (blockIdx.x >> 3);
    const int it = nid & 15;       // 16 i-tiles of 64 rows
    const int bh = nid >> 4;
    const int b = bh >> 3;
    const int h = bh & 7;

    const size_t vbase = (size_t)bh * 98304;

    for (int j = tid; j < 1024; j += 256) {
        const float* p2 = f2p + (size_t)(b * 1024 + j) * 48 + h * 6;
        float s = ((p2[0] + p2[1]) + (p2[2] + p2[3])) + (p2[4] + p2[5]);
        g2_s[j] = (mask[b * 1024 + j] != 0) ? s * LOG2E : -20000.f;
    }

    const float* p1 = f1p + (size_t)(b * 1024 + it * 64 + w * 16 + fcr) * 48 + h * 6;
    const float f1v = (((p1[0] + p1[1]) + (p1[2] + p1[3])) + (p1[4] + p1[5])) * LOG2E;

#pragma unroll
    for (int r = 0; r < 6; ++r) {
        const int s = r * 256 + tid;           // 16B slot 0..1535
        gload16(Vb + vbase + (size_t)s * 8, &Vs[0][s * 8]);
    }

    f32x4 acc[6];
#pragma unroll
    for (int ft = 0; ft < 6; ++ft) acc[ft] = (f32x4){0.f, 0.f, 0.f, 0.f};
    float ls = 0.f;

    int buf = 0;
    for (int c = 0; c < 8; ++c) {
        __syncthreads();
        if (c < 7) {
#pragma unroll
            for (int r = 0; r < 6; ++r) {
                const int s = r * 256 + tid;
                gload16(Vb + vbase + (size_t)(c + 1) * 12288 + (size_t)s * 8,
                        &Vs[buf ^ 1][s * 8]);
            }
        }
        const unsigned short* vsb = &Vs[buf][0];
#pragma unroll
        for (int ks = 0; ks < 4; ++ks) {
            s8 af;
            const int jb = c * 128 + ks * 32 + kg * 8;
            float4 ga = *(const float4*)&g2_s[jb];
            float4 gb = *(const float4*)&g2_s[jb + 4];
            float g[8] = {ga.x, ga.y, ga.z, ga.w, gb.x, gb.y, gb.z, gb.w};
#pragma unroll
            for (int e = 0; e < 8; ++e) {
                float t = f1v + g[e];
                float lr = fmaxf(t, 0.f) + ALPHA * fminf(t, 0.f);
                float pe = exp2f(lr);
                ls += pe;
                af[e] = (short)f2bf(pe);
            }
            const unsigned short* vp = vsb + ((ks * 4 + kg) * 6) * 128 + fcr * 8;
#pragma unroll
            for (int ft = 0; ft < 6; ++ft) {
                us8 bvu = *(const us8*)(vp + ft * 128);
                acc[ft] = __builtin_amdgcn_mfma_f32_16x16x32_bf16(
                    af, (s8)bvu, acc[ft], 0, 0, 0);
            }
        }
        buf ^= 1;
    }

    ls += __shfl_xor(ls, 16);
    ls += __shfl_xor(ls, 32);
    float inv[4];
#pragma unroll
    for (int r = 0; r < 4; ++r) inv[r] = 1.0f / __shfl(ls, kg * 4 + r);

    const int irow0 = it * 64 + w * 16 + kg * 4;
#pragma unroll
    for (int r = 0; r < 4; ++r) {
        const size_t ob = (size_t)(b * 1024 + irow0 + r) * 768 + h * 96 + fcr;
#pragma unroll
        for (int ft = 0; ft < 6; ++ft) {
            out[ob + ft * 16] = acc[ft][r] * inv[r];
        }
    }
}

extern "C" void kernel_launch(void* const* d_in, const int* in_sizes, int n_in,
                              void* d_out, int out_size, void* d_ws, size_t ws_size,
                              hipStream_t stream) {
    const float* X = (const float*)d_in[0];
    const int* mask = (const int*)d_in[1];
    const float* W = (const float*)d_in[2];
    const float* a = (const float*)d_in[3];
    float* out = (float*)d_out;
    char* ws = (char*)d_ws;

    unsigned short* Vb = (unsigned short*)(ws + VB_OFFB);
    float* f1p = (float*)(ws + F1P_OFFB);
    float* f2p = (float*)(ws + F2P_OFFB);

    gemm_np<<<768, 256, 0, stream>>>(X, W, a, Vb, f1p, f2p);
    attn8_k<<<512, 256, 0, stream>>>(Vb, f1p, f2p, mask, out);
}